// Round 7
// baseline (268.742 us; speedup 1.0000x reference)
//
#include <hip/hip_runtime.h>
#include <hip/hip_bf16.h>

#define KN 16384
#define KD 1024
#define NB (KN / 128)   // 128 tile-blocks per dimension

typedef __attribute__((ext_vector_type(4)))  int   i32x4;
typedef __attribute__((ext_vector_type(8)))  int   i32x8;
typedef __attribute__((ext_vector_type(16))) float f32x16;  // MFMA 32x32 accumulator
typedef __attribute__((ext_vector_type(2)))  unsigned int u32x2;

// Global MX scale 2^-6: e8m0 byte = 127-6 = 121 = 0x79 (replicated, opsel-proof).
#define SCALE_M6 0x79797979
#define FMT_FP4  4   // cbsz/blgp format code: e2m1

// FP4 FRAGMENT-NATIVE BLOCKED LAYOUT for xn (8 MB):
//   row-group g = row/16, k-block kb = k/128; chunk(g,kb) = 1024 B at (g*8+kb)*1024
//   lane f = quad*16 + row%16 owns bytes [f*16,f*16+16) = k-nibbles quad*32..+32
//   (k even -> LOW nibble).
//   16x16 fragment load = ONE dwordx4 at g*8192 + kb*1024 + lane*16.
//   32x32x64 fragment load (R7): lane l needs row l&31, k in [(l>>5)*32,+32) of a
//   64-k step ks -> SAME layout, per-lane const offset
//     lofs = ((l>>4)&1)*8192 + (l>>5)*256 + (l&15)*16, step offset = ks*512.
//   (verified algebraically: kb*1024 + ((ks&1)*2+(l>>5))*256 == ks*512 + (l>>5)*256)
//
// ⚠ Session ledger (k_nn_argmax GEMM):
//   R1: unified VGPR/AGPR file — occupancy = (archVGPR + 64 accAGPR)/wave.
//   R2: forcing __launch_bounds__(256,4) spills ~8 regs -> scratch traffic
//       (FETCH 35->92 MB), dur +16%. Never cap below what the loop needs.
//   R0(4 w/SIMD) == R1(3 w/SIMD) at 120 µs: NOT occupancy-bound at 3-4 w/SIMD.
//   R3: per-kb LDS staging + per-kb barrier: 141 µs despite halved L2 traffic.
//   R4: persistent-A strips: 11% occ + L2 thrash: 259 µs.
//   R5: 2-stage register pipeline: VGPR 120 -> 2 w/SIMD: 137 µs.
//   => barrier-free flatmm @ 3 w/SIMD = 120 µs is the measured structure optimum.
//   R7 (this): SAME structure, MFMA shape 16x16x128 -> 32x32x64. µbench rate
//      9099 vs 7228 TF (+26%), MFMA slots per kb halve (16->8), load traffic
//      identical, k_normalize layout UNTOUCHED. Epilogue remapped to the
//      32x32 C/D layout: col = lane&31, row = (reg&3)+8*(reg>>2)+4*(lane>>5).
__device__ __forceinline__ i32x8 ldg_frag4(const unsigned char* p) {
  const i32x4 v = *(const i32x4*)p;  // pure SSA — never write a local through
                                     // a casted pointer (R4-R6 SROA lesson)
  return __builtin_shufflevector(v, v, 0, 1, 2, 3, -1, -1, -1, -1);
}

// ---- packed (dot, index) -> ONE monotonic u32 --------------------------------
// dots ∈ [-1.2, 1.2]. fma(v, 0.125, 3.0) ∈ [2.85, 3.15): constant fp32 exponent,
// so (bits << 9) is a monotone 23-bit key. Top 18 bits value, low 14 idx^0x3FFF
// (ties -> SMALLEST index, matching jnp.argmax). Resolution 6.1e-5 — 80x below
// fp4 dot noise (~5e-3) that already yielded absmax 0.
#define IDX_MASK 0x3FFFu
#define VAL_MASK 0xFFFFC000u

// fp32 (pre-scaled by 64/||row||) -> fp4 e2m1 nibble, RNE via boolean-sum chain
// (fallback path; HW cvt_scalef32_pk_fp4 replaces it when available)
__device__ __forceinline__ unsigned fp4n(float x) {
  const float a = fabsf(x);
  unsigned c = (unsigned)(a >= 0.25f) + (unsigned)(a >= 0.75f)
             + (unsigned)(a >= 1.25f) + (unsigned)(a >= 1.75f)
             + (unsigned)(a >= 2.5f)  + (unsigned)(a >= 3.5f)
             + (unsigned)(a >= 5.0f);
  return c | ((__float_as_uint(x) >> 28) & 8u);
}

#if defined(__has_builtin)
#if __has_builtin(__builtin_amdgcn_cvt_scalef32_pk_fp4_f32)
#define HW_FP4 1
#endif
#endif

// ---------------- row L2-normalize, fp32 -> fp4 e2m1, blocked layout --------
// One WAVE per row (4 rows/block). Lane L owns 16 CONSECUTIVE k-elements
// [16L, 16L+16) -> 16 nibbles = ONE contiguous 8 B store at
//   kb = L>>3, quad = (L&7)>>1, byte-in-frag = 8*(L&1):
//   addr = g*8192 + kb*1024 + (quad*16 + row%16)*16 + 8*(L&1)
// (same layout equations as the original 4x2B-store version; byte-identical.)
__global__ __launch_bounds__(256) void k_normalize(const float* __restrict__ x,
                                                   unsigned char* __restrict__ xn,
                                                   unsigned* __restrict__ best) {
  const int lane = threadIdx.x & 63;
  const int wave = threadIdx.x >> 6;
  const int row  = (blockIdx.x << 2) + wave;
  if (lane == 0) best[row] = 0u;  // all real candidates have value-field >> 0
  const float4* xr = (const float4*)(x + (size_t)row * KD);
  const float4 v0 = xr[(lane << 2) + 0];
  const float4 v1 = xr[(lane << 2) + 1];
  const float4 v2 = xr[(lane << 2) + 2];
  const float4 v3 = xr[(lane << 2) + 3];
  float ss = v0.x * v0.x + v0.y * v0.y + v0.z * v0.z + v0.w * v0.w
           + v1.x * v1.x + v1.y * v1.y + v1.z * v1.z + v1.w * v1.w
           + v2.x * v2.x + v2.y * v2.y + v2.z * v2.z + v2.w * v2.w
           + v3.x * v3.x + v3.y * v3.y + v3.z * v3.z + v3.w * v3.w;
#pragma unroll
  for (int off = 32; off > 0; off >>= 1) ss += __shfl_xor(ss, off);
  const float scale = 64.0f / fmaxf(sqrtf(ss), 1e-8f);  // F.normalize eps + 2^6 pre-scale
  const float s0  = v0.x * scale, s1  = v0.y * scale, s2  = v0.z * scale, s3  = v0.w * scale;
  const float s4  = v1.x * scale, s5  = v1.y * scale, s6  = v1.z * scale, s7  = v1.w * scale;
  const float s8  = v2.x * scale, s9  = v2.y * scale, s10 = v2.z * scale, s11 = v2.w * scale;
  const float s12 = v3.x * scale, s13 = v3.y * scale, s14 = v3.z * scale, s15 = v3.w * scale;
  unsigned w0 = 0u, w1 = 0u;
#ifdef HW_FP4
  // HW RNE quant: scale operand 1.0f is neutral; src0 -> low nibble,
  // byte_sel -> byte b. (R6 measured: absmax 0 vs fp32 reference.)
  w0 = __builtin_amdgcn_cvt_scalef32_pk_fp4_f32(w0, s0,  s1,  1.0f, 0);
  w0 = __builtin_amdgcn_cvt_scalef32_pk_fp4_f32(w0, s2,  s3,  1.0f, 1);
  w0 = __builtin_amdgcn_cvt_scalef32_pk_fp4_f32(w0, s4,  s5,  1.0f, 2);
  w0 = __builtin_amdgcn_cvt_scalef32_pk_fp4_f32(w0, s6,  s7,  1.0f, 3);
  w1 = __builtin_amdgcn_cvt_scalef32_pk_fp4_f32(w1, s8,  s9,  1.0f, 0);
  w1 = __builtin_amdgcn_cvt_scalef32_pk_fp4_f32(w1, s10, s11, 1.0f, 1);
  w1 = __builtin_amdgcn_cvt_scalef32_pk_fp4_f32(w1, s12, s13, 1.0f, 2);
  w1 = __builtin_amdgcn_cvt_scalef32_pk_fp4_f32(w1, s14, s15, 1.0f, 3);
#else
  w0 = (fp4n(s0)  | (fp4n(s1)  << 4)) | ((fp4n(s2)  | (fp4n(s3)  << 4)) << 8)
     | ((fp4n(s4) | (fp4n(s5)  << 4)) << 16) | ((fp4n(s6)  | (fp4n(s7)  << 4)) << 24);
  w1 = (fp4n(s8)  | (fp4n(s9)  << 4)) | ((fp4n(s10) | (fp4n(s11) << 4)) << 8)
     | ((fp4n(s12)| (fp4n(s13) << 4)) << 16) | ((fp4n(s14) | (fp4n(s15) << 4)) << 24);
#endif
  unsigned char* base = xn + ((size_t)(row >> 4) << 13) + ((size_t)(lane >> 3) << 10)
                      + ((((lane & 6) << 3) + (row & 15)) << 4) + ((lane & 1) << 3);
  *(u32x2*)base = (u32x2){w0, w1};
}

// ---- two-sided argmax epilogue on the 64x64 wave tile (32x32 C/D layout) ----
// acc[m][n] is a 32x32 fragment: col = lane&31, row = (reg&3)+8*(reg>>2)+4*hi,
// hi = lane>>5 (m101-verified mapping). Row-reduce = 5-step shfl_xor within the
// 32-lane half (off<32 never crosses bit5); lanes 0 and 32 hold DIFFERENT rows
// and both atomic. Col-reduce: in-lane chain over (m,reg) + one shfl_xor(32).
// DIAG=true (bx==by): mask self-dot, skip col pass (covered by the transpose
// wave within the same block). DIAG=false: no mask compares.
template <bool DIAG>
__device__ __forceinline__ void epilogue32(const f32x16 (&acc)[2][2], int by, int bx,
                                           int wm, int wn, int l31, int hi,
                                           unsigned* __restrict__ best) {
  const int rowbase = (by << 7) + wm * 64 + (hi << 2);  // +4*hi folded in
  const int colbase = (bx << 7) + wn * 64 + l31;
  unsigned cm0 = 0u, cm1 = 0u;
#pragma unroll
  for (int m = 0; m < 2; m++) {
#pragma unroll
    for (int reg = 0; reg < 16; reg++) {
      const int grow = rowbase + m * 32 + (reg & 3) + ((reg >> 2) << 3);
      const unsigned grx = (unsigned)grow ^ IDX_MASK;
      unsigned rm = 0u;
#pragma unroll
      for (int n = 0; n < 2; n++) {
        const int gcol = colbase + n * 32;
        unsigned t = (__float_as_uint(fmaf(acc[m][n][reg], 0.125f, 3.0f)) << 9) & VAL_MASK;
        if (DIAG && gcol == grow) t = 0u;  // self-similarity: lose to everything
        const unsigned rc = t | ((unsigned)gcol ^ IDX_MASK);
        const unsigned cc = t | grx;
        rm = rm > rc ? rm : rc;
        if (n == 0) cm0 = cm0 > cc ? cm0 : cc;
        else        cm1 = cm1 > cc ? cm1 : cc;
      }
#pragma unroll
      for (int off = 1; off < 32; off <<= 1) {  // reduce within the 32-lane half
        const unsigned o = __shfl_xor(rm, off);
        rm = rm > o ? rm : o;
      }
      if (l31 == 0) atomicMax(best + grow, rm);  // lanes 0 & 32: distinct rows
    }
  }
  if (!DIAG) {  // col argmax via symmetry: merge the two hi-halves
    unsigned o = __shfl_xor(cm0, 32);
    cm0 = cm0 > o ? cm0 : o;
    o = __shfl_xor(cm1, 32);
    cm1 = cm1 > o ? cm1 : o;
    if (hi == 0) {
      atomicMax(best + colbase, cm0);
      atomicMax(best + colbase + 32, cm1);
    }
  }
}

// ---------------- fused symmetric NT-GEMM (fp4, MX-scaled) + two-sided argmax
// R1 structure (measured optimum): barrier-free flatmm, no LDS, no syncthreads,
// circulant cover bx = by + d mod NB, 8x8 (by,d) chunks round-robin over XCDs.
// R7: 32x32x64 MFMA. Per 64-k step ks: 4 dwordx4 loads + 4 MFMAs; 16 steps.
// Same total load traffic as the 16x16 version; 26% faster matrix pipe.
__global__ __launch_bounds__(256, 2) void k_nn_argmax(const unsigned char* __restrict__ xn,
                                                      unsigned* __restrict__ best) {
  const int id = blockIdx.x;
  int d, by;
  if (id < 8192) {                      // main region: d in [0,64)
    const int o   = id & 7;             // XCD (round-robin heuristic)
    const int idp = id >> 3;            // per-XCD sequence
    const int k   = idp >> 6;           // chunk counter (0..15)
    const int p   = idp & 63;           // position within 8x8 chunk
    const int q   = o + (k << 3);       // global chunk id (0..127)
    by = ((q & 15) << 3) + (p & 7);     // by-chunk * 8 + row-in-chunk
    d  = ((q >> 4) << 3) + (p >> 3);    // d-chunk * 8 + d-in-chunk
  } else {                              // tail: d == 64, by in [0,64)
    d  = NB / 2;
    by = id - 8192;
  }
  const int bx = (by + d) & (NB - 1);   // col tile

  const int tid  = threadIdx.x;
  const int lane = tid & 63;
  const int wave = tid >> 6;
  const int wm   = wave >> 1;           // wave row (0..1)
  const int wn   = wave & 1;            // wave col (0..1)
  const int l31  = lane & 31;
  const int hi   = lane >> 5;

  f32x16 acc[2][2];
#pragma unroll
  for (int m = 0; m < 2; m++)
#pragma unroll
    for (int n = 0; n < 2; n++)
#pragma unroll
      for (int r = 0; r < 16; r++) acc[m][n][r] = 0.f;

  // 32x32 fragment addressing out of the 16-row blocked layout:
  // lane l -> row l&31 (rowgroup split on bit4), k-half l>>5 (quad offset 256).
  const int lofs = (((lane >> 4) & 1) << 13) + (hi << 8) + ((lane & 15) << 4);
  const unsigned char* pa0 = xn + ((size_t)((by << 3) + (wm << 2)) << 13) + lofs;
  const unsigned char* pa1 = pa0 + 16384;   // m=1: +32 rows = +2 rowgroups
  const unsigned char* pb0 = xn + ((size_t)((bx << 3) + (wn << 2)) << 13) + lofs;
  const unsigned char* pb1 = pb0 + 16384;

#pragma unroll 4
  for (int ks = 0; ks < 16; ks++) {     // 64-k steps; byte offset = ks*512
    const int ko = ks << 9;
    const i32x8 a0 = ldg_frag4(pa0 + ko);
    const i32x8 a1 = ldg_frag4(pa1 + ko);
    const i32x8 b0 = ldg_frag4(pb0 + ko);
    const i32x8 b1 = ldg_frag4(pb1 + ko);
    acc[0][0] = __builtin_amdgcn_mfma_scale_f32_32x32x64_f8f6f4(a0, b0, acc[0][0], FMT_FP4, FMT_FP4, 0, SCALE_M6, 0, SCALE_M6);
    acc[1][0] = __builtin_amdgcn_mfma_scale_f32_32x32x64_f8f6f4(a1, b0, acc[1][0], FMT_FP4, FMT_FP4, 0, SCALE_M6, 0, SCALE_M6);
    acc[0][1] = __builtin_amdgcn_mfma_scale_f32_32x32x64_f8f6f4(a0, b1, acc[0][1], FMT_FP4, FMT_FP4, 0, SCALE_M6, 0, SCALE_M6);
    acc[1][1] = __builtin_amdgcn_mfma_scale_f32_32x32x64_f8f6f4(a1, b1, acc[1][1], FMT_FP4, FMT_FP4, 0, SCALE_M6, 0, SCALE_M6);
  }

  if (d == 0) epilogue32<true>(acc, by, bx, wm, wn, l31, hi, best);
  else        epilogue32<false>(acc, by, bx, wm, wn, l31, hi, best);
}

// ---------------- distance to NN + -log (wave per row, plain store) ---------
__global__ __launch_bounds__(256) void k_dist(const float* __restrict__ x,
                                              const unsigned* __restrict__ best,
                                              float* __restrict__ rowlog) {
  const int lane = threadIdx.x & 63;
  const int wave = threadIdx.x >> 6;
  const int row  = (blockIdx.x << 2) + wave;
  const int nb   = (int)((~best[row]) & IDX_MASK);  // decode complemented index
  const float4* ar = (const float4*)(x + (size_t)row * KD);
  const float4* br = (const float4*)(x + (size_t)nb * KD);
  float ss = 0.f;
#pragma unroll
  for (int q = 0; q < 4; q++) {
    const float4 a = ar[lane + 64 * q];
    const float4 b = br[lane + 64 * q];
    const float dx = a.x - b.x + 1e-6f;  // torch PairwiseDistance eps on the diff
    const float dy = a.y - b.y + 1e-6f;
    const float dz = a.z - b.z + 1e-6f;
    const float dw = a.w - b.w + 1e-6f;
    ss += dx * dx + dy * dy + dz * dz + dw * dw;
  }
#pragma unroll
  for (int off = 32; off > 0; off >>= 1) ss += __shfl_xor(ss, off);
  if (lane == 0) rowlog[row] = -logf(sqrtf(ss));
}

// ---------------- final mean (1024 threads, 16 waves) ----------------
__global__ __launch_bounds__(1024) void k_final(const float* __restrict__ rowlog,
                                                float* __restrict__ out) {
  const int tid = threadIdx.x;
  float s = 0.f;
  for (int i = tid; i < KN; i += 1024) s += rowlog[i];
#pragma unroll
  for (int off = 32; off > 0; off >>= 1) s += __shfl_down(s, off);
  __shared__ float ws[16];
  if ((tid & 63) == 0) ws[tid >> 6] = s;
  __syncthreads();
  if (tid == 0) {
    float t = 0.f;
#pragma unroll
    for (int i = 0; i < 16; i++) t += ws[i];
    out[0] = t / (float)KN;
  }
}

extern "C" void kernel_launch(void* const* d_in, const int* in_sizes, int n_in,
                              void* d_out, int out_size, void* d_ws, size_t ws_size,
                              hipStream_t stream) {
  const float* x = (const float*)d_in[0];
  float* out = (float*)d_out;

  char* ws = (char*)d_ws;
  unsigned char* xn = (unsigned char*)ws;                                 // 8 MB fp4 (blocked)
  unsigned* best = (unsigned*)(ws + (size_t)KN * KD / 2);                 // 64 KB (u32 packed)
  float* rowlog = (float*)(ws + (size_t)KN * KD / 2 + (size_t)KN * 4);    // 64 KB

  k_normalize<<<KN / 4, 256, 0, stream>>>(x, xn, best);
  k_nn_argmax<<<8192 + 64, 256, 0, stream>>>(xn, best);  // supertiled 1D cover
  k_dist<<<KN / 4, 256, 0, stream>>>(x, best, rowlog);
  k_final<<<1, 1024, 0, stream>>>(rowlog, out);
}

// Round 8
// 226.819 us; speedup vs baseline: 1.1848x; 1.1848x over previous
//
#include <hip/hip_runtime.h>
#include <hip/hip_bf16.h>

#define KN 16384
#define KD 1024
#define NB (KN / 128)   // 128 tile-blocks per dimension

typedef __attribute__((ext_vector_type(4))) int   i32x4;
typedef __attribute__((ext_vector_type(8))) int   i32x8;
typedef __attribute__((ext_vector_type(4))) float f32x4;  // MFMA 16x16 accumulator
typedef __attribute__((ext_vector_type(2))) unsigned int u32x2;

// Global MX scale 2^-6: e8m0 byte = 127-6 = 121 = 0x79 (replicated, opsel-proof).
#define SCALE_M6 0x79797979
#define FMT_FP4  4   // cbsz/blgp format code: e2m1

// FP4 FRAGMENT-NATIVE BLOCKED LAYOUT for xn (8 MB):
//   row-group g = row/16, k-block kb = k/128; chunk(g,kb) = 1024 B at (g*8+kb)*1024
//   lane f = quad*16 + row%16 owns bytes [f*16,f*16+16) = k-nibbles quad*32..+32
//   (k even -> LOW nibble). GEMM fragment load = ONE dwordx4 at base + f*16.
//
// ⚠ Session ledger (k_nn_argmax GEMM — R1 structure is the measured optimum):
//   R1: unified VGPR/AGPR file — occupancy = (archVGPR + 64 accAGPR)/wave.
//   R2: forcing __launch_bounds__(256,4) spills ~8 regs -> scratch traffic
//       (FETCH 35->92 MB), dur +16%. Never cap below what the loop needs.
//   R0(4 w/SIMD) == R1(3 w/SIMD) at 120 µs: NOT occupancy-bound at 3-4 w/SIMD.
//   R3: per-kb LDS staging + per-kb barrier: 141 µs despite halved L2 traffic.
//   R4: persistent-A strips: 11% occ + L2 thrash: 259 µs.
//   R5: 2-stage register pipeline: VGPR 120 -> 2 w/SIMD: 137 µs.
//   R7: 32x32x64 shape: 167 µs. Per-step MFMA burst fell 357 -> 141 cyc per
//       load round; latency exposed. At shallow K (8 steps), per-step MFMA
//       issue DENSITY beats per-MFMA rate. 16x16x128 stays.
//   => barrier-free flatmm @ 3 w/SIMD, 16x16x128 = 120 µs. LEAVE IT.
//   R8 (this): GEMM untouched. k_normalize block->row remap: all 4 blocks of
//       a 16-row group share one XCD (was: consecutive bids -> 4 different
//       XCDs partially writing the SAME 128B lines -> partial-line HBM write
//       amplification on the 8 MB fp4 output). Bytes written are identical.
__device__ __forceinline__ i32x8 ldg_frag4(const unsigned char* p) {
  const i32x4 v = *(const i32x4*)p;  // pure SSA — never write a local through
                                     // a casted pointer (R4-R6 SROA lesson)
  return __builtin_shufflevector(v, v, 0, 1, 2, 3, -1, -1, -1, -1);
}

// ---- packed (dot, index) -> ONE monotonic u32 --------------------------------
// dots ∈ [-1.2, 1.2]. fma(v, 0.125, 3.0) ∈ [2.85, 3.15): constant fp32 exponent,
// so (bits << 9) is a monotone 23-bit key. Top 18 bits value, low 14 idx^0x3FFF
// (ties -> SMALLEST index, matching jnp.argmax). Resolution 6.1e-5 — 80x below
// fp4 dot noise (~5e-3) that already yielded absmax 0.
#define IDX_MASK 0x3FFFu
#define VAL_MASK 0xFFFFC000u

// fp32 (pre-scaled by 64/||row||) -> fp4 e2m1 nibble, RNE via boolean-sum chain
// (fallback path; HW cvt_scalef32_pk_fp4 replaces it when available)
__device__ __forceinline__ unsigned fp4n(float x) {
  const float a = fabsf(x);
  unsigned c = (unsigned)(a >= 0.25f) + (unsigned)(a >= 0.75f)
             + (unsigned)(a >= 1.25f) + (unsigned)(a >= 1.75f)
             + (unsigned)(a >= 2.5f)  + (unsigned)(a >= 3.5f)
             + (unsigned)(a >= 5.0f);
  return c | ((__float_as_uint(x) >> 28) & 8u);
}

#if defined(__has_builtin)
#if __has_builtin(__builtin_amdgcn_cvt_scalef32_pk_fp4_f32)
#define HW_FP4 1
#endif
#endif

// ---------------- row L2-normalize, fp32 -> fp4 e2m1, blocked layout --------
// One WAVE per row (4 rows/block). Lane L owns 16 CONSECUTIVE k-elements
// [16L, 16L+16) -> 16 nibbles = ONE contiguous 8 B store at
//   kb = L>>3, quad = (L&7)>>1, byte-in-frag = 8*(L&1):
//   addr = g*8192 + kb*1024 + (quad*16 + row%16)*16 + 8*(L&1)
// R8 block->row remap: bid = o + t*8 + u*32 (o = XCD 0..7, t = 4-row slice
// 0..3, u = per-XCD group 0..127) -> rowgroup g = o*128 + u, row = g*16 +
// t*4 + wave. The 4 blocks writing one 16-row group are ≡ o (mod 8) -> same
// XCD -> full 128B lines assembled within one L2 (kills partial-line writes).
__global__ __launch_bounds__(256) void k_normalize(const float* __restrict__ x,
                                                   unsigned char* __restrict__ xn,
                                                   unsigned* __restrict__ best) {
  const int lane = threadIdx.x & 63;
  const int wave = threadIdx.x >> 6;
  const int bid  = blockIdx.x;
  const int g    = ((bid & 7) << 7) + (bid >> 5);   // rowgroup, XCD-grouped
  const int sub  = (bid >> 3) & 3;                  // 4-row slice within group
  const int row  = (g << 4) + (sub << 2) + wave;
  if (lane == 0) best[row] = 0u;  // all real candidates have value-field >> 0
  const float4* xr = (const float4*)(x + (size_t)row * KD);
  const float4 v0 = xr[(lane << 2) + 0];
  const float4 v1 = xr[(lane << 2) + 1];
  const float4 v2 = xr[(lane << 2) + 2];
  const float4 v3 = xr[(lane << 2) + 3];
  float ss = v0.x * v0.x + v0.y * v0.y + v0.z * v0.z + v0.w * v0.w
           + v1.x * v1.x + v1.y * v1.y + v1.z * v1.z + v1.w * v1.w
           + v2.x * v2.x + v2.y * v2.y + v2.z * v2.z + v2.w * v2.w
           + v3.x * v3.x + v3.y * v3.y + v3.z * v3.z + v3.w * v3.w;
#pragma unroll
  for (int off = 32; off > 0; off >>= 1) ss += __shfl_xor(ss, off);
  const float scale = 64.0f / fmaxf(sqrtf(ss), 1e-8f);  // F.normalize eps + 2^6 pre-scale
  const float s0  = v0.x * scale, s1  = v0.y * scale, s2  = v0.z * scale, s3  = v0.w * scale;
  const float s4  = v1.x * scale, s5  = v1.y * scale, s6  = v1.z * scale, s7  = v1.w * scale;
  const float s8  = v2.x * scale, s9  = v2.y * scale, s10 = v2.z * scale, s11 = v2.w * scale;
  const float s12 = v3.x * scale, s13 = v3.y * scale, s14 = v3.z * scale, s15 = v3.w * scale;
  unsigned w0 = 0u, w1 = 0u;
#ifdef HW_FP4
  // HW RNE quant: scale operand 1.0f is neutral; src0 -> low nibble,
  // byte_sel -> byte b. (R6 measured: absmax 0 vs fp32 reference.)
  w0 = __builtin_amdgcn_cvt_scalef32_pk_fp4_f32(w0, s0,  s1,  1.0f, 0);
  w0 = __builtin_amdgcn_cvt_scalef32_pk_fp4_f32(w0, s2,  s3,  1.0f, 1);
  w0 = __builtin_amdgcn_cvt_scalef32_pk_fp4_f32(w0, s4,  s5,  1.0f, 2);
  w0 = __builtin_amdgcn_cvt_scalef32_pk_fp4_f32(w0, s6,  s7,  1.0f, 3);
  w1 = __builtin_amdgcn_cvt_scalef32_pk_fp4_f32(w1, s8,  s9,  1.0f, 0);
  w1 = __builtin_amdgcn_cvt_scalef32_pk_fp4_f32(w1, s10, s11, 1.0f, 1);
  w1 = __builtin_amdgcn_cvt_scalef32_pk_fp4_f32(w1, s12, s13, 1.0f, 2);
  w1 = __builtin_amdgcn_cvt_scalef32_pk_fp4_f32(w1, s14, s15, 1.0f, 3);
#else
  w0 = (fp4n(s0)  | (fp4n(s1)  << 4)) | ((fp4n(s2)  | (fp4n(s3)  << 4)) << 8)
     | ((fp4n(s4) | (fp4n(s5)  << 4)) << 16) | ((fp4n(s6)  | (fp4n(s7)  << 4)) << 24);
  w1 = (fp4n(s8)  | (fp4n(s9)  << 4)) | ((fp4n(s10) | (fp4n(s11) << 4)) << 8)
     | ((fp4n(s12)| (fp4n(s13) << 4)) << 16) | ((fp4n(s14) | (fp4n(s15) << 4)) << 24);
#endif
  unsigned char* base = xn + ((size_t)(row >> 4) << 13) + ((size_t)(lane >> 3) << 10)
                      + ((((lane & 6) << 3) + (row & 15)) << 4) + ((lane & 1) << 3);
  *(u32x2*)base = (u32x2){w0, w1};
}

// ---- two-sided argmax epilogue on the 64x64 wave tile ------------------------
// C/D layout (16x16): col = lane&15, row = quad*4+reg. DIAG=true (bx==by, 64 of
// 8256 blocks): mask self-dot, skip col pass. DIAG=false: no mask compares.
template <bool DIAG>
__device__ __forceinline__ void epilogue(const f32x4 (&acc)[4][4], int by, int bx,
                                         int wm, int wn, int quad, int l15,
                                         unsigned* __restrict__ best) {
  const int rowbase = (by << 7) + wm * 64 + (quad << 2);
  const int colbase = (bx << 7) + wn * 64 + l15;
  unsigned cm0 = 0u, cm1 = 0u, cm2 = 0u, cm3 = 0u;
#pragma unroll
  for (int i = 0; i < 4; i++) {
#pragma unroll
    for (int r = 0; r < 4; r++) {
      const int grow = rowbase + i * 16 + r;
      const unsigned grx = (unsigned)grow ^ IDX_MASK;
      unsigned rm = 0u;
#pragma unroll
      for (int j = 0; j < 4; j++) {
        const int gcol = colbase + j * 16;
        unsigned t = (__float_as_uint(fmaf(acc[i][j][r], 0.125f, 3.0f)) << 9) & VAL_MASK;
        if (DIAG && gcol == grow) t = 0u;  // self-similarity: lose to everything
        const unsigned rc = t | ((unsigned)gcol ^ IDX_MASK);
        const unsigned cc = t | grx;
        rm = rm > rc ? rm : rc;
        if (j == 0) cm0 = cm0 > cc ? cm0 : cc;
        if (j == 1) cm1 = cm1 > cc ? cm1 : cc;
        if (j == 2) cm2 = cm2 > cc ? cm2 : cc;
        if (j == 3) cm3 = cm3 > cc ? cm3 : cc;
      }
#pragma unroll
      for (int off = 1; off < 16; off <<= 1) {  // reduce over the 16 l15 lanes
        const unsigned o = __shfl_xor(rm, off);
        rm = rm > o ? rm : o;
      }
      if (l15 == 0) atomicMax(best + grow, rm);
    }
  }
  if (!DIAG) {  // col argmax via symmetry — quads hold same cols, different rows
    unsigned cm[4] = {cm0, cm1, cm2, cm3};
#pragma unroll
    for (int j = 0; j < 4; j++) {
      unsigned o = __shfl_xor(cm[j], 16);
      cm[j] = cm[j] > o ? cm[j] : o;
      o = __shfl_xor(cm[j], 32);
      cm[j] = cm[j] > o ? cm[j] : o;
      if (quad == 0) atomicMax(best + colbase + j * 16, cm[j]);
    }
  }
}

// ---------------- fused symmetric NT-GEMM (fp4, MX-scaled) + two-sided argmax
// R1 structure (measured session optimum, 120 µs): barrier-free flatmm on the
// fp4 blocked layout, one dwordx4 per fragment, no LDS, no __syncthreads.
// Circulant cover bx = by + d mod NB; 8x8 (by,d) chunks round-robin over XCDs.
__global__ __launch_bounds__(256, 2) void k_nn_argmax(const unsigned char* __restrict__ xn,
                                                      unsigned* __restrict__ best) {
  const int id = blockIdx.x;
  int d, by;
  if (id < 8192) {                      // main region: d in [0,64)
    const int o   = id & 7;             // XCD (round-robin heuristic)
    const int idp = id >> 3;            // per-XCD sequence
    const int k   = idp >> 6;           // chunk counter (0..15)
    const int p   = idp & 63;           // position within 8x8 chunk
    const int q   = o + (k << 3);       // global chunk id (0..127)
    by = ((q & 15) << 3) + (p & 7);     // by-chunk * 8 + row-in-chunk
    d  = ((q >> 4) << 3) + (p >> 3);    // d-chunk * 8 + d-in-chunk
  } else {                              // tail: d == 64, by in [0,64)
    d  = NB / 2;
    by = id - 8192;
  }
  const int bx = (by + d) & (NB - 1);   // col tile

  const int tid  = threadIdx.x;
  const int lane = tid & 63;
  const int wave = tid >> 6;
  const int wm   = wave >> 1;           // wave row (0..1)
  const int wn   = wave & 1;            // wave col (0..1)
  const int quad = lane >> 4;
  const int l15  = lane & 15;

  f32x4 acc[4][4];
#pragma unroll
  for (int i = 0; i < 4; i++)
#pragma unroll
    for (int j = 0; j < 4; j++) acc[i][j] = (f32x4){0.f, 0.f, 0.f, 0.f};

  // fragment bases: row-group g = by*8 + wm*4 + i; 8192 B per group (8 kb x 1 KB)
  const unsigned char* pa = xn + ((size_t)((by << 3) + (wm << 2)) << 13) + (lane << 4);
  const unsigned char* pb = xn + ((size_t)((bx << 3) + (wn << 2)) << 13) + (lane << 4);

#pragma unroll 2
  for (int kb = 0; kb < 8; kb++) {
    const int ko = kb << 10;
    const i32x8 a0 = ldg_frag4(pa + ko);
    const i32x8 a1 = ldg_frag4(pa + (1 << 13) + ko);
    const i32x8 a2 = ldg_frag4(pa + (2 << 13) + ko);
    const i32x8 a3 = ldg_frag4(pa + (3 << 13) + ko);
    const i32x8 b0 = ldg_frag4(pb + ko);
    const i32x8 b1 = ldg_frag4(pb + (1 << 13) + ko);
    const i32x8 b2 = ldg_frag4(pb + (2 << 13) + ko);
    const i32x8 b3 = ldg_frag4(pb + (3 << 13) + ko);
    acc[0][0] = __builtin_amdgcn_mfma_scale_f32_16x16x128_f8f6f4(a0, b0, acc[0][0], FMT_FP4, FMT_FP4, 0, SCALE_M6, 0, SCALE_M6);
    acc[1][0] = __builtin_amdgcn_mfma_scale_f32_16x16x128_f8f6f4(a1, b0, acc[1][0], FMT_FP4, FMT_FP4, 0, SCALE_M6, 0, SCALE_M6);
    acc[2][0] = __builtin_amdgcn_mfma_scale_f32_16x16x128_f8f6f4(a2, b0, acc[2][0], FMT_FP4, FMT_FP4, 0, SCALE_M6, 0, SCALE_M6);
    acc[3][0] = __builtin_amdgcn_mfma_scale_f32_16x16x128_f8f6f4(a3, b0, acc[3][0], FMT_FP4, FMT_FP4, 0, SCALE_M6, 0, SCALE_M6);
    acc[0][1] = __builtin_amdgcn_mfma_scale_f32_16x16x128_f8f6f4(a0, b1, acc[0][1], FMT_FP4, FMT_FP4, 0, SCALE_M6, 0, SCALE_M6);
    acc[1][1] = __builtin_amdgcn_mfma_scale_f32_16x16x128_f8f6f4(a1, b1, acc[1][1], FMT_FP4, FMT_FP4, 0, SCALE_M6, 0, SCALE_M6);
    acc[2][1] = __builtin_amdgcn_mfma_scale_f32_16x16x128_f8f6f4(a2, b1, acc[2][1], FMT_FP4, FMT_FP4, 0, SCALE_M6, 0, SCALE_M6);
    acc[3][1] = __builtin_amdgcn_mfma_scale_f32_16x16x128_f8f6f4(a3, b1, acc[3][1], FMT_FP4, FMT_FP4, 0, SCALE_M6, 0, SCALE_M6);
    acc[0][2] = __builtin_amdgcn_mfma_scale_f32_16x16x128_f8f6f4(a0, b2, acc[0][2], FMT_FP4, FMT_FP4, 0, SCALE_M6, 0, SCALE_M6);
    acc[1][2] = __builtin_amdgcn_mfma_scale_f32_16x16x128_f8f6f4(a1, b2, acc[1][2], FMT_FP4, FMT_FP4, 0, SCALE_M6, 0, SCALE_M6);
    acc[2][2] = __builtin_amdgcn_mfma_scale_f32_16x16x128_f8f6f4(a2, b2, acc[2][2], FMT_FP4, FMT_FP4, 0, SCALE_M6, 0, SCALE_M6);
    acc[3][2] = __builtin_amdgcn_mfma_scale_f32_16x16x128_f8f6f4(a3, b2, acc[3][2], FMT_FP4, FMT_FP4, 0, SCALE_M6, 0, SCALE_M6);
    acc[0][3] = __builtin_amdgcn_mfma_scale_f32_16x16x128_f8f6f4(a0, b3, acc[0][3], FMT_FP4, FMT_FP4, 0, SCALE_M6, 0, SCALE_M6);
    acc[1][3] = __builtin_amdgcn_mfma_scale_f32_16x16x128_f8f6f4(a1, b3, acc[1][3], FMT_FP4, FMT_FP4, 0, SCALE_M6, 0, SCALE_M6);
    acc[2][3] = __builtin_amdgcn_mfma_scale_f32_16x16x128_f8f6f4(a2, b3, acc[2][3], FMT_FP4, FMT_FP4, 0, SCALE_M6, 0, SCALE_M6);
    acc[3][3] = __builtin_amdgcn_mfma_scale_f32_16x16x128_f8f6f4(a3, b3, acc[3][3], FMT_FP4, FMT_FP4, 0, SCALE_M6, 0, SCALE_M6);
  }

  if (d == 0) epilogue<true>(acc, by, bx, wm, wn, quad, l15, best);
  else        epilogue<false>(acc, by, bx, wm, wn, quad, l15, best);
}

// ---------------- distance to NN + -log (wave per row, plain store) ---------
__global__ __launch_bounds__(256) void k_dist(const float* __restrict__ x,
                                              const unsigned* __restrict__ best,
                                              float* __restrict__ rowlog) {
  const int lane = threadIdx.x & 63;
  const int wave = threadIdx.x >> 6;
  const int row  = (blockIdx.x << 2) + wave;
  const int nb   = (int)((~best[row]) & IDX_MASK);  // decode complemented index
  const float4* ar = (const float4*)(x + (size_t)row * KD);
  const float4* br = (const float4*)(x + (size_t)nb * KD);
  float ss = 0.f;
#pragma unroll
  for (int q = 0; q < 4; q++) {
    const float4 a = ar[lane + 64 * q];
    const float4 b = br[lane + 64 * q];
    const float dx = a.x - b.x + 1e-6f;  // torch PairwiseDistance eps on the diff
    const float dy = a.y - b.y + 1e-6f;
    const float dz = a.z - b.z + 1e-6f;
    const float dw = a.w - b.w + 1e-6f;
    ss += dx * dx + dy * dy + dz * dz + dw * dw;
  }
#pragma unroll
  for (int off = 32; off > 0; off >>= 1) ss += __shfl_xor(ss, off);
  if (lane == 0) rowlog[row] = -logf(sqrtf(ss));
}

// ---------------- final mean (1024 threads, 16 waves) ----------------
__global__ __launch_bounds__(1024) void k_final(const float* __restrict__ rowlog,
                                                float* __restrict__ out) {
  const int tid = threadIdx.x;
  float s = 0.f;
  for (int i = tid; i < KN; i += 1024) s += rowlog[i];
#pragma unroll
  for (int off = 32; off > 0; off >>= 1) s += __shfl_down(s, off);
  __shared__ float ws[16];
  if ((tid & 63) == 0) ws[tid >> 6] = s;
  __syncthreads();
  if (tid == 0) {
    float t = 0.f;
#pragma unroll
    for (int i = 0; i < 16; i++) t += ws[i];
    out[0] = t / (float)KN;
  }
}

extern "C" void kernel_launch(void* const* d_in, const int* in_sizes, int n_in,
                              void* d_out, int out_size, void* d_ws, size_t ws_size,
                              hipStream_t stream) {
  const float* x = (const float*)d_in[0];
  float* out = (float*)d_out;

  char* ws = (char*)d_ws;
  unsigned char* xn = (unsigned char*)ws;                                 // 8 MB fp4 (blocked)
  unsigned* best = (unsigned*)(ws + (size_t)KN * KD / 2);                 // 64 KB (u32 packed)
  float* rowlog = (float*)(ws + (size_t)KN * KD / 2 + (size_t)KN * 4);    // 64 KB

  k_normalize<<<KN / 4, 256, 0, stream>>>(x, xn, best);
  k_nn_argmax<<<8192 + 64, 256, 0, stream>>>(xn, best);  // supertiled 1D cover
  k_dist<<<KN / 4, 256, 0, stream>>>(x, best, rowlog);
  k_final<<<1, 1024, 0, stream>>>(rowlog, out);
}

// Round 9
// 219.159 us; speedup vs baseline: 1.2262x; 1.0350x over previous
//
#include <hip/hip_runtime.h>
#include <hip/hip_bf16.h>

#define KN 16384
#define KD 1024
#define NB (KN / 128)   // 128 tile-blocks per dimension

typedef __attribute__((ext_vector_type(4))) int   i32x4;
typedef __attribute__((ext_vector_type(8))) int   i32x8;
typedef __attribute__((ext_vector_type(4))) float f32x4;  // MFMA 16x16 accumulator
typedef __attribute__((ext_vector_type(2))) unsigned int u32x2;

// Global MX scale 2^-6: e8m0 byte = 127-6 = 121 = 0x79 (replicated, opsel-proof).
#define SCALE_M6 0x79797979
#define FMT_FP4  4   // cbsz/blgp format code: e2m1

// FP4 FRAGMENT-NATIVE BLOCKED LAYOUT for xn (8 MB):
//   row-group g = row/16, k-block kb = k/128; chunk(g,kb) = 1024 B at (g*8+kb)*1024
//   lane f = quad*16 + row%16 owns bytes [f*16,f*16+16) = k-nibbles quad*32..+32
//   (k even -> LOW nibble). GEMM fragment load = ONE dwordx4 at base + f*16.
//
// ⚠ Session ledger (k_nn_argmax GEMM — R1 structure is the measured optimum):
//   R1: unified VGPR/AGPR file — occupancy = (archVGPR + 64 accAGPR)/wave.
//   R2: forcing __launch_bounds__(256,4) spills ~8 regs -> scratch traffic
//       (FETCH 35->92 MB), dur +16%. Never cap below what the loop needs.
//   R0(4 w/SIMD) == R1(3 w/SIMD) at 120 µs: NOT occupancy-bound at 3-4 w/SIMD.
//   R3: per-kb LDS staging + per-kb barrier: 141 µs despite halved L2 traffic.
//   R4: persistent-A strips: 11% occ + L2 thrash: 259 µs.
//   R5: 2-stage register pipeline: VGPR 120 -> 2 w/SIMD: 137 µs.
//   R7: 32x32x64 shape: 167 µs. At shallow K (8 steps), per-step MFMA issue
//       DENSITY beats per-MFMA rate. 16x16x128 stays.
//   R8: normalize XCD-write remap unmeasurable; GEMM inter-run noise is
//       ±4-5 µs on identical code. Deltas < 5 µs are not actionable.
//   => barrier-free flatmm @ 3 w/SIMD, 16x16x128 ≈ 120 µs. Structure FROZEN.
//   R9 (this): single-variable A/B vs R6: s_setprio(1) around the MFMA
//       cluster (T5). Prereq is wave phase diversity — null on barrier-locked
//       GEMM (m190) but +4-7% on barrier-free independent waves (m191). Our
//       flatmm is the m191 structure: no barriers, mixed-phase waves per CU.
__device__ __forceinline__ i32x8 ldg_frag4(const unsigned char* p) {
  const i32x4 v = *(const i32x4*)p;  // pure SSA — never write a local through
                                     // a casted pointer (R4-R6 SROA lesson)
  return __builtin_shufflevector(v, v, 0, 1, 2, 3, -1, -1, -1, -1);
}

// ---- packed (dot, index) -> ONE monotonic u32 --------------------------------
// dots ∈ [-1.2, 1.2]. fma(v, 0.125, 3.0) ∈ [2.85, 3.15): constant fp32 exponent,
// so (bits << 9) is a monotone 23-bit key. Top 18 bits value, low 14 idx^0x3FFF
// (ties -> SMALLEST index, matching jnp.argmax). Resolution 6.1e-5 — 80x below
// fp4 dot noise (~5e-3) that already yielded absmax 0.
#define IDX_MASK 0x3FFFu
#define VAL_MASK 0xFFFFC000u

// fp32 (pre-scaled by 64/||row||) -> fp4 e2m1 nibble, RNE via boolean-sum chain
// (fallback path; HW cvt_scalef32_pk_fp4 replaces it when available)
__device__ __forceinline__ unsigned fp4n(float x) {
  const float a = fabsf(x);
  unsigned c = (unsigned)(a >= 0.25f) + (unsigned)(a >= 0.75f)
             + (unsigned)(a >= 1.25f) + (unsigned)(a >= 1.75f)
             + (unsigned)(a >= 2.5f)  + (unsigned)(a >= 3.5f)
             + (unsigned)(a >= 5.0f);
  return c | ((__float_as_uint(x) >> 28) & 8u);
}

#if defined(__has_builtin)
#if __has_builtin(__builtin_amdgcn_cvt_scalef32_pk_fp4_f32)
#define HW_FP4 1
#endif
#endif

// ---------------- row L2-normalize, fp32 -> fp4 e2m1, blocked layout --------
// One WAVE per row (4 rows/block). Lane L owns 16 CONSECUTIVE k-elements
// [16L, 16L+16) -> 16 nibbles = ONE contiguous 8 B store at
//   kb = L>>3, quad = (L&7)>>1, byte-in-frag = 8*(L&1):
//   addr = g*8192 + kb*1024 + (quad*16 + row%16)*16 + 8*(L&1)
// (R6 configuration — best measured total, 221.6 µs.)
__global__ __launch_bounds__(256) void k_normalize(const float* __restrict__ x,
                                                   unsigned char* __restrict__ xn,
                                                   unsigned* __restrict__ best) {
  const int lane = threadIdx.x & 63;
  const int wave = threadIdx.x >> 6;
  const int row  = (blockIdx.x << 2) + wave;
  if (lane == 0) best[row] = 0u;  // all real candidates have value-field >> 0
  const float4* xr = (const float4*)(x + (size_t)row * KD);
  const float4 v0 = xr[(lane << 2) + 0];
  const float4 v1 = xr[(lane << 2) + 1];
  const float4 v2 = xr[(lane << 2) + 2];
  const float4 v3 = xr[(lane << 2) + 3];
  float ss = v0.x * v0.x + v0.y * v0.y + v0.z * v0.z + v0.w * v0.w
           + v1.x * v1.x + v1.y * v1.y + v1.z * v1.z + v1.w * v1.w
           + v2.x * v2.x + v2.y * v2.y + v2.z * v2.z + v2.w * v2.w
           + v3.x * v3.x + v3.y * v3.y + v3.z * v3.z + v3.w * v3.w;
#pragma unroll
  for (int off = 32; off > 0; off >>= 1) ss += __shfl_xor(ss, off);
  const float scale = 64.0f / fmaxf(sqrtf(ss), 1e-8f);  // F.normalize eps + 2^6 pre-scale
  const float s0  = v0.x * scale, s1  = v0.y * scale, s2  = v0.z * scale, s3  = v0.w * scale;
  const float s4  = v1.x * scale, s5  = v1.y * scale, s6  = v1.z * scale, s7  = v1.w * scale;
  const float s8  = v2.x * scale, s9  = v2.y * scale, s10 = v2.z * scale, s11 = v2.w * scale;
  const float s12 = v3.x * scale, s13 = v3.y * scale, s14 = v3.z * scale, s15 = v3.w * scale;
  unsigned w0 = 0u, w1 = 0u;
#ifdef HW_FP4
  // HW RNE quant: scale operand 1.0f is neutral; src0 -> low nibble,
  // byte_sel -> byte b. (R6 measured: absmax 0 vs fp32 reference.)
  w0 = __builtin_amdgcn_cvt_scalef32_pk_fp4_f32(w0, s0,  s1,  1.0f, 0);
  w0 = __builtin_amdgcn_cvt_scalef32_pk_fp4_f32(w0, s2,  s3,  1.0f, 1);
  w0 = __builtin_amdgcn_cvt_scalef32_pk_fp4_f32(w0, s4,  s5,  1.0f, 2);
  w0 = __builtin_amdgcn_cvt_scalef32_pk_fp4_f32(w0, s6,  s7,  1.0f, 3);
  w1 = __builtin_amdgcn_cvt_scalef32_pk_fp4_f32(w1, s8,  s9,  1.0f, 0);
  w1 = __builtin_amdgcn_cvt_scalef32_pk_fp4_f32(w1, s10, s11, 1.0f, 1);
  w1 = __builtin_amdgcn_cvt_scalef32_pk_fp4_f32(w1, s12, s13, 1.0f, 2);
  w1 = __builtin_amdgcn_cvt_scalef32_pk_fp4_f32(w1, s14, s15, 1.0f, 3);
#else
  w0 = (fp4n(s0)  | (fp4n(s1)  << 4)) | ((fp4n(s2)  | (fp4n(s3)  << 4)) << 8)
     | ((fp4n(s4) | (fp4n(s5)  << 4)) << 16) | ((fp4n(s6)  | (fp4n(s7)  << 4)) << 24);
  w1 = (fp4n(s8)  | (fp4n(s9)  << 4)) | ((fp4n(s10) | (fp4n(s11) << 4)) << 8)
     | ((fp4n(s12)| (fp4n(s13) << 4)) << 16) | ((fp4n(s14) | (fp4n(s15) << 4)) << 24);
#endif
  unsigned char* base = xn + ((size_t)(row >> 4) << 13) + ((size_t)(lane >> 3) << 10)
                      + ((((lane & 6) << 3) + (row & 15)) << 4) + ((lane & 1) << 3);
  *(u32x2*)base = (u32x2){w0, w1};
}

// ---- two-sided argmax epilogue on the 64x64 wave tile ------------------------
// C/D layout (16x16): col = lane&15, row = quad*4+reg. DIAG=true (bx==by, 64 of
// 8256 blocks): mask self-dot, skip col pass. DIAG=false: no mask compares.
template <bool DIAG>
__device__ __forceinline__ void epilogue(const f32x4 (&acc)[4][4], int by, int bx,
                                         int wm, int wn, int quad, int l15,
                                         unsigned* __restrict__ best) {
  const int rowbase = (by << 7) + wm * 64 + (quad << 2);
  const int colbase = (bx << 7) + wn * 64 + l15;
  unsigned cm0 = 0u, cm1 = 0u, cm2 = 0u, cm3 = 0u;
#pragma unroll
  for (int i = 0; i < 4; i++) {
#pragma unroll
    for (int r = 0; r < 4; r++) {
      const int grow = rowbase + i * 16 + r;
      const unsigned grx = (unsigned)grow ^ IDX_MASK;
      unsigned rm = 0u;
#pragma unroll
      for (int j = 0; j < 4; j++) {
        const int gcol = colbase + j * 16;
        unsigned t = (__float_as_uint(fmaf(acc[i][j][r], 0.125f, 3.0f)) << 9) & VAL_MASK;
        if (DIAG && gcol == grow) t = 0u;  // self-similarity: lose to everything
        const unsigned rc = t | ((unsigned)gcol ^ IDX_MASK);
        const unsigned cc = t | grx;
        rm = rm > rc ? rm : rc;
        if (j == 0) cm0 = cm0 > cc ? cm0 : cc;
        if (j == 1) cm1 = cm1 > cc ? cm1 : cc;
        if (j == 2) cm2 = cm2 > cc ? cm2 : cc;
        if (j == 3) cm3 = cm3 > cc ? cm3 : cc;
      }
#pragma unroll
      for (int off = 1; off < 16; off <<= 1) {  // reduce over the 16 l15 lanes
        const unsigned o = __shfl_xor(rm, off);
        rm = rm > o ? rm : o;
      }
      if (l15 == 0) atomicMax(best + grow, rm);
    }
  }
  if (!DIAG) {  // col argmax via symmetry — quads hold same cols, different rows
    unsigned cm[4] = {cm0, cm1, cm2, cm3};
#pragma unroll
    for (int j = 0; j < 4; j++) {
      unsigned o = __shfl_xor(cm[j], 16);
      cm[j] = cm[j] > o ? cm[j] : o;
      o = __shfl_xor(cm[j], 32);
      cm[j] = cm[j] > o ? cm[j] : o;
      if (quad == 0) atomicMax(best + colbase + j * 16, cm[j]);
    }
  }
}

// ---------------- fused symmetric NT-GEMM (fp4, MX-scaled) + two-sided argmax
// R1 structure (measured session optimum, ~120 µs): barrier-free flatmm on the
// fp4 blocked layout, one dwordx4 per fragment, no LDS, no __syncthreads.
// Circulant cover bx = by + d mod NB; 8x8 (by,d) chunks round-robin over XCDs.
// R9: s_setprio(1) wraps the MFMA cluster — biases CU issue arbitration toward
// the wave currently in its MFMA burst (waves are barrier-free and phase-mixed,
// the m191-positive structure).
__global__ __launch_bounds__(256, 2) void k_nn_argmax(const unsigned char* __restrict__ xn,
                                                      unsigned* __restrict__ best) {
  const int id = blockIdx.x;
  int d, by;
  if (id < 8192) {                      // main region: d in [0,64)
    const int o   = id & 7;             // XCD (round-robin heuristic)
    const int idp = id >> 3;            // per-XCD sequence
    const int k   = idp >> 6;           // chunk counter (0..15)
    const int p   = idp & 63;           // position within 8x8 chunk
    const int q   = o + (k << 3);       // global chunk id (0..127)
    by = ((q & 15) << 3) + (p & 7);     // by-chunk * 8 + row-in-chunk
    d  = ((q >> 4) << 3) + (p >> 3);    // d-chunk * 8 + d-in-chunk
  } else {                              // tail: d == 64, by in [0,64)
    d  = NB / 2;
    by = id - 8192;
  }
  const int bx = (by + d) & (NB - 1);   // col tile

  const int tid  = threadIdx.x;
  const int lane = tid & 63;
  const int wave = tid >> 6;
  const int wm   = wave >> 1;           // wave row (0..1)
  const int wn   = wave & 1;            // wave col (0..1)
  const int quad = lane >> 4;
  const int l15  = lane & 15;

  f32x4 acc[4][4];
#pragma unroll
  for (int i = 0; i < 4; i++)
#pragma unroll
    for (int j = 0; j < 4; j++) acc[i][j] = (f32x4){0.f, 0.f, 0.f, 0.f};

  // fragment bases: row-group g = by*8 + wm*4 + i; 8192 B per group (8 kb x 1 KB)
  const unsigned char* pa = xn + ((size_t)((by << 3) + (wm << 2)) << 13) + (lane << 4);
  const unsigned char* pb = xn + ((size_t)((bx << 3) + (wn << 2)) << 13) + (lane << 4);

#pragma unroll 2
  for (int kb = 0; kb < 8; kb++) {
    const int ko = kb << 10;
    const i32x8 a0 = ldg_frag4(pa + ko);
    const i32x8 a1 = ldg_frag4(pa + (1 << 13) + ko);
    const i32x8 a2 = ldg_frag4(pa + (2 << 13) + ko);
    const i32x8 a3 = ldg_frag4(pa + (3 << 13) + ko);
    const i32x8 b0 = ldg_frag4(pb + ko);
    const i32x8 b1 = ldg_frag4(pb + (1 << 13) + ko);
    const i32x8 b2 = ldg_frag4(pb + (2 << 13) + ko);
    const i32x8 b3 = ldg_frag4(pb + (3 << 13) + ko);
    __builtin_amdgcn_s_setprio(1);  // favor this wave while the matrix pipe is fed
    acc[0][0] = __builtin_amdgcn_mfma_scale_f32_16x16x128_f8f6f4(a0, b0, acc[0][0], FMT_FP4, FMT_FP4, 0, SCALE_M6, 0, SCALE_M6);
    acc[1][0] = __builtin_amdgcn_mfma_scale_f32_16x16x128_f8f6f4(a1, b0, acc[1][0], FMT_FP4, FMT_FP4, 0, SCALE_M6, 0, SCALE_M6);
    acc[2][0] = __builtin_amdgcn_mfma_scale_f32_16x16x128_f8f6f4(a2, b0, acc[2][0], FMT_FP4, FMT_FP4, 0, SCALE_M6, 0, SCALE_M6);
    acc[3][0] = __builtin_amdgcn_mfma_scale_f32_16x16x128_f8f6f4(a3, b0, acc[3][0], FMT_FP4, FMT_FP4, 0, SCALE_M6, 0, SCALE_M6);
    acc[0][1] = __builtin_amdgcn_mfma_scale_f32_16x16x128_f8f6f4(a0, b1, acc[0][1], FMT_FP4, FMT_FP4, 0, SCALE_M6, 0, SCALE_M6);
    acc[1][1] = __builtin_amdgcn_mfma_scale_f32_16x16x128_f8f6f4(a1, b1, acc[1][1], FMT_FP4, FMT_FP4, 0, SCALE_M6, 0, SCALE_M6);
    acc[2][1] = __builtin_amdgcn_mfma_scale_f32_16x16x128_f8f6f4(a2, b1, acc[2][1], FMT_FP4, FMT_FP4, 0, SCALE_M6, 0, SCALE_M6);
    acc[3][1] = __builtin_amdgcn_mfma_scale_f32_16x16x128_f8f6f4(a3, b1, acc[3][1], FMT_FP4, FMT_FP4, 0, SCALE_M6, 0, SCALE_M6);
    acc[0][2] = __builtin_amdgcn_mfma_scale_f32_16x16x128_f8f6f4(a0, b2, acc[0][2], FMT_FP4, FMT_FP4, 0, SCALE_M6, 0, SCALE_M6);
    acc[1][2] = __builtin_amdgcn_mfma_scale_f32_16x16x128_f8f6f4(a1, b2, acc[1][2], FMT_FP4, FMT_FP4, 0, SCALE_M6, 0, SCALE_M6);
    acc[2][2] = __builtin_amdgcn_mfma_scale_f32_16x16x128_f8f6f4(a2, b2, acc[2][2], FMT_FP4, FMT_FP4, 0, SCALE_M6, 0, SCALE_M6);
    acc[3][2] = __builtin_amdgcn_mfma_scale_f32_16x16x128_f8f6f4(a3, b2, acc[3][2], FMT_FP4, FMT_FP4, 0, SCALE_M6, 0, SCALE_M6);
    acc[0][3] = __builtin_amdgcn_mfma_scale_f32_16x16x128_f8f6f4(a0, b3, acc[0][3], FMT_FP4, FMT_FP4, 0, SCALE_M6, 0, SCALE_M6);
    acc[1][3] = __builtin_amdgcn_mfma_scale_f32_16x16x128_f8f6f4(a1, b3, acc[1][3], FMT_FP4, FMT_FP4, 0, SCALE_M6, 0, SCALE_M6);
    acc[2][3] = __builtin_amdgcn_mfma_scale_f32_16x16x128_f8f6f4(a2, b3, acc[2][3], FMT_FP4, FMT_FP4, 0, SCALE_M6, 0, SCALE_M6);
    acc[3][3] = __builtin_amdgcn_mfma_scale_f32_16x16x128_f8f6f4(a3, b3, acc[3][3], FMT_FP4, FMT_FP4, 0, SCALE_M6, 0, SCALE_M6);
    __builtin_amdgcn_s_setprio(0);
  }

  if (d == 0) epilogue<true>(acc, by, bx, wm, wn, quad, l15, best);
  else        epilogue<false>(acc, by, bx, wm, wn, quad, l15, best);
}

// ---------------- distance to NN + -log (wave per row, plain store) ---------
__global__ __launch_bounds__(256) void k_dist(const float* __restrict__ x,
                                              const unsigned* __restrict__ best,
                                              float* __restrict__ rowlog) {
  const int lane = threadIdx.x & 63;
  const int wave = threadIdx.x >> 6;
  const int row  = (blockIdx.x << 2) + wave;
  const int nb   = (int)((~best[row]) & IDX_MASK);  // decode complemented index
  const float4* ar = (const float4*)(x + (size_t)row * KD);
  const float4* br = (const float4*)(x + (size_t)nb * KD);
  float ss = 0.f;
#pragma unroll
  for (int q = 0; q < 4; q++) {
    const float4 a = ar[lane + 64 * q];
    const float4 b = br[lane + 64 * q];
    const float dx = a.x - b.x + 1e-6f;  // torch PairwiseDistance eps on the diff
    const float dy = a.y - b.y + 1e-6f;
    const float dz = a.z - b.z + 1e-6f;
    const float dw = a.w - b.w + 1e-6f;
    ss += dx * dx + dy * dy + dz * dz + dw * dw;
  }
#pragma unroll
  for (int off = 32; off > 0; off >>= 1) ss += __shfl_xor(ss, off);
  if (lane == 0) rowlog[row] = -logf(sqrtf(ss));
}

// ---------------- final mean (1024 threads, 16 waves) ----------------
__global__ __launch_bounds__(1024) void k_final(const float* __restrict__ rowlog,
                                                float* __restrict__ out) {
  const int tid = threadIdx.x;
  float s = 0.f;
  for (int i = tid; i < KN; i += 1024) s += rowlog[i];
#pragma unroll
  for (int off = 32; off > 0; off >>= 1) s += __shfl_down(s, off);
  __shared__ float ws[16];
  if ((tid & 63) == 0) ws[tid >> 6] = s;
  __syncthreads();
  if (tid == 0) {
    float t = 0.f;
#pragma unroll
    for (int i = 0; i < 16; i++) t += ws[i];
    out[0] = t / (float)KN;
  }
}

extern "C" void kernel_launch(void* const* d_in, const int* in_sizes, int n_in,
                              void* d_out, int out_size, void* d_ws, size_t ws_size,
                              hipStream_t stream) {
  const float* x = (const float*)d_in[0];
  float* out = (float*)d_out;

  char* ws = (char*)d_ws;
  unsigned char* xn = (unsigned char*)ws;                                 // 8 MB fp4 (blocked)
  unsigned* best = (unsigned*)(ws + (size_t)KN * KD / 2);                 // 64 KB (u32 packed)
  float* rowlog = (float*)(ws + (size_t)KN * KD / 2 + (size_t)KN * 4);    // 64 KB

  k_normalize<<<KN / 4, 256, 0, stream>>>(x, xn, best);
  k_nn_argmax<<<8192 + 64, 256, 0, stream>>>(xn, best);  // supertiled 1D cover
  k_dist<<<KN / 4, 256, 0, stream>>>(x, best, rowlog);
  k_final<<<1, 1024, 0, stream>>>(rowlog, out);
}